// Round 17
// baseline (82.817 us; speedup 1.0000x reference)
//
#include <hip/hip_runtime.h>

#define TOKS 65536
#define ED 64
#define NE 1024
#define CH_STRIDE 4096      // 64*64
#define B_STRIDE 262144     // 64*64*64

typedef __bf16 bf16x8 __attribute__((ext_vector_type(8)));
typedef float f32x16 __attribute__((ext_vector_type(16)));
typedef unsigned short ushort_t;
typedef unsigned int uint_t;

// ws layout:
//   efrag    @ 0      : 32ct x 4ks x 64lane x 8 bf16 (hi of -2*emb) [128 KB]
//   enorm    @ 131072 : 1024 f32 (np-pairwise ||e||^2, exact)        [4 KB]
//   hist     @ 135168 : 1024 i32                                     [4 KB]
//   lossPart @ 143360 : 2048 f64                                     [16 KB]

__device__ __forceinline__ ushort_t f2bf(float x) {
    uint_t u = __float_as_uint(x);
    uint_t r = u + 0x7FFFu + ((u >> 16) & 1u);   // RNE
    return (ushort_t)(r >> 16);
}

// ---- prep E: wave per code (unchanged, validated).
__global__ __launch_bounds__(256) void vq_prep_e(const float* __restrict__ emb,
                                                 ushort_t* __restrict__ efrag,
                                                 float* __restrict__ enorm,
                                                 int* __restrict__ hist) {
    const int tid = threadIdx.x;
    const int w = tid >> 6, lane = tid & 63;
    const int j = blockIdx.x * 4 + w;

    const float e = emb[j * 64 + lane];
    const float sq = __fmul_rn(e, e);
    float acc = sq;
    acc = __fadd_rn(acc, __shfl_down(sq, 8, 64));
    acc = __fadd_rn(acc, __shfl_down(sq, 16, 64));
    acc = __fadd_rn(acc, __shfl_down(sq, 24, 64));
    acc = __fadd_rn(acc, __shfl_down(sq, 32, 64));
    acc = __fadd_rn(acc, __shfl_down(sq, 40, 64));
    acc = __fadd_rn(acc, __shfl_down(sq, 48, 64));
    acc = __fadd_rn(acc, __shfl_down(sq, 56, 64));
    float x = __fadd_rn(acc, __shfl_down(acc, 1, 64));
    float y = __fadd_rn(x, __shfl_down(x, 2, 64));
    float zn = __fadd_rn(y, __shfl_down(y, 4, 64));
    if (lane == 0) enorm[j] = zn;

    const ushort_t h = f2bf(-2.0f * e);
    const int ct = j >> 5, m = j & 31;
    const int ks = lane >> 4, kh = (lane >> 3) & 1, i = lane & 7;
    efrag[(size_t)((ct * 4 + ks) * 512) + (m + 32 * kh) * 8 + i] = h;

    if (blockIdx.x < 4) hist[blockIdx.x * 256 + tid] = 0;
}

// ---- fused: pass1 min-only MFMA scan + pass2 gated recompute/extract with
// inline exact rescore + gather/hist/loss/zq. 32-token blocks, 2048 blocks.
__global__ __launch_bounds__(256, 4) void vq_main(
    const float* __restrict__ z,
    const ushort_t* __restrict__ efrag,
    const float* __restrict__ enorm,
    const float* __restrict__ emb,
    float* __restrict__ zq,
    float* __restrict__ out_idx,
    int* __restrict__ hist,
    double* __restrict__ lossPart) {
    __shared__ float z_s[32][68];                 // [token][channel], 8.7 KB
    __shared__ float sminf[4][32];                // per (wave, token) d~ min
    __shared__ float s_zn[32];
    __shared__ unsigned long long s_res[32];      // lex-min (d_bits<<10 | j)
    __shared__ double wsum[4];

    const int tid = threadIdx.x;
    const int w = tid >> 6, lane = tid & 63;
    const int t0 = blockIdx.x * 32;
    const int b = t0 >> 12, hw0 = t0 & 4095;
    const float* zbase = z + (size_t)b * B_STRIDE + hw0;

    // stage z once: thread (c, u0) loads 8 floats, transposes to token-major
    {
        const int c = tid >> 2, u0 = (tid & 3) * 8;
        const float* src = zbase + (size_t)c * CH_STRIDE + u0;
        float4 f0 = *(const float4*)(src);
        float4 f1 = *(const float4*)(src + 4);
        z_s[u0 + 0][c] = f0.x; z_s[u0 + 1][c] = f0.y;
        z_s[u0 + 2][c] = f0.z; z_s[u0 + 3][c] = f0.w;
        z_s[u0 + 4][c] = f1.x; z_s[u0 + 5][c] = f1.y;
        z_s[u0 + 6][c] = f1.z; z_s[u0 + 7][c] = f1.w;
    }
    if (tid < 32) s_res[tid] = 0xFFFFFFFFFFFFFFFFull;
    __syncthreads();

    const int n = lane & 31, kh = lane >> 5;

    // B-frag from LDS (b128 contiguous rows)
    bf16x8 zb[4];
    #pragma unroll
    for (int ks = 0; ks < 4; ++ks) {
        float4 a0 = *(const float4*)&z_s[n][ks * 16 + kh * 8];
        float4 a1 = *(const float4*)&z_s[n][ks * 16 + kh * 8 + 4];
        const float av[8] = {a0.x, a0.y, a0.z, a0.w, a1.x, a1.y, a1.z, a1.w};
        #pragma unroll
        for (int i = 0; i < 8; ++i) {
            union { ushort_t u; __bf16 bh; } cv;
            cv.u = f2bf(av[i]);
            zb[ks][i] = cv.bh;
        }
    }

    const bf16x8* eg = (const bf16x8*)efrag;

    // ---- pass 1: per-ct min of d~ only (no index tracking, no keys)
    float mct[8];
    #pragma unroll
    for (int ct = 0; ct < 8; ++ct) {
        const int gct = w * 8 + ct;
        bf16x8 ah0 = eg[(size_t)(gct * 4 + 0) * 64 + lane];
        bf16x8 ah1 = eg[(size_t)(gct * 4 + 1) * 64 + lane];
        bf16x8 ah2 = eg[(size_t)(gct * 4 + 2) * 64 + lane];
        bf16x8 ah3 = eg[(size_t)(gct * 4 + 3) * 64 + lane];
        f32x16 acc;
        #pragma unroll
        for (int r = 0; r < 16; ++r) acc[r] = 0.25f;
        acc = __builtin_amdgcn_mfma_f32_32x32x16_bf16(ah0, zb[0], acc, 0, 0, 0);
        acc = __builtin_amdgcn_mfma_f32_32x32x16_bf16(ah1, zb[1], acc, 0, 0, 0);
        acc = __builtin_amdgcn_mfma_f32_32x32x16_bf16(ah2, zb[2], acc, 0, 0, 0);
        acc = __builtin_amdgcn_mfma_f32_32x32x16_bf16(ah3, zb[3], acc, 0, 0, 0);
        float m0 = fminf(fminf(acc[0], acc[1]), fminf(acc[2], acc[3]));
        float m1 = fminf(fminf(acc[4], acc[5]), fminf(acc[6], acc[7]));
        float m2 = fminf(fminf(acc[8], acc[9]), fminf(acc[10], acc[11]));
        float m3 = fminf(fminf(acc[12], acc[13]), fminf(acc[14], acc[15]));
        mct[ct] = fminf(fminf(m0, m1), fminf(m2, m3));
    }
    {
        float vmin = mct[0];
        #pragma unroll
        for (int ct = 1; ct < 8; ++ct) vmin = fminf(vmin, mct[ct]);
        vmin = fminf(vmin, __shfl_xor(vmin, 32, 64));  // merge kh halves
        if (kh == 0) sminf[w][n] = vmin;
    }
    __syncthreads();

    // znorm: np pairwise exact (8 threads/token, slice p, xor 1/2/4 = np tree)
    {
        const int tok = tid >> 3, p = tid & 7;
        float a = z_s[tok][p];
        float racc = __fmul_rn(a, a);
        #pragma unroll
        for (int i = 1; i < 8; ++i) {
            float av = z_s[tok][p + 8 * i];
            racc = __fadd_rn(racc, __fmul_rn(av, av));
        }
        float x1 = __fadd_rn(racc, __shfl_xor(racc, 1, 64));
        float y1 = __fadd_rn(x1, __shfl_xor(x1, 2, 64));
        float znv = __fadd_rn(y1, __shfl_xor(y1, 4, 64));
        if (p == 0) s_zn[tok] = znv;
    }
    __syncthreads();

    // ---- pass 2: gated recompute + extract + inline exact rescore
    const float thr = fminf(fminf(sminf[0][n], sminf[1][n]),
                            fminf(sminf[2][n], sminf[3][n])) + 4.0e-4f;
    const float zn = s_zn[n];
    #pragma unroll 1
    for (int ct = 0; ct < 8; ++ct) {
        if (__any(mct[ct] <= thr)) {
            const int gct = w * 8 + ct;
            bf16x8 ah0 = eg[(size_t)(gct * 4 + 0) * 64 + lane];
            bf16x8 ah1 = eg[(size_t)(gct * 4 + 1) * 64 + lane];
            bf16x8 ah2 = eg[(size_t)(gct * 4 + 2) * 64 + lane];
            bf16x8 ah3 = eg[(size_t)(gct * 4 + 3) * 64 + lane];
            f32x16 acc;
            #pragma unroll
            for (int r = 0; r < 16; ++r) acc[r] = 0.25f;
            acc = __builtin_amdgcn_mfma_f32_32x32x16_bf16(ah0, zb[0], acc, 0, 0, 0);
            acc = __builtin_amdgcn_mfma_f32_32x32x16_bf16(ah1, zb[1], acc, 0, 0, 0);
            acc = __builtin_amdgcn_mfma_f32_32x32x16_bf16(ah2, zb[2], acc, 0, 0, 0);
            acc = __builtin_amdgcn_mfma_f32_32x32x16_bf16(ah3, zb[3], acc, 0, 0, 0);
            #pragma unroll
            for (int r = 0; r < 16; ++r) {
                if (acc[r] <= thr) {               // rare: exact rescore inline
                    const int j = gct * 32 + (r & 3) + 8 * (r >> 2) + 4 * kh;
                    const float* e = emb + (size_t)j * 64;
                    float a0 = 0.f;
                    #pragma unroll
                    for (int k4 = 0; k4 < 16; ++k4) {
                        float4 z4 = *(const float4*)&z_s[n][k4 * 4];
                        float4 e4 = *(const float4*)(e + k4 * 4);
                        a0 = __fmaf_rn(z4.x, e4.x, a0);
                        a0 = __fmaf_rn(z4.y, e4.y, a0);
                        a0 = __fmaf_rn(z4.z, e4.z, a0);
                        a0 = __fmaf_rn(z4.w, e4.w, a0);
                    }
                    float d = __fsub_rn(__fadd_rn(zn, enorm[j]), 2.0f * a0);
                    unsigned long long key =
                        ((unsigned long long)__float_as_uint(d) << 10)
                        | (unsigned long long)j;
                    atomicMin(&s_res[n], key);
                }
            }
        }
    }
    __syncthreads();

    // gather + loss: 8 threads/token, 8 contiguous channels each
    const int tok = tid >> 3, p = tid & 7;
    const int bj = (int)(s_res[tok] & 1023u);
    if (p == 0) {
        out_idx[t0 + tok] = (float)bj;
        atomicAdd(&hist[bj], 1);
    }
    double ls = 0.0;
    {
        const float* e = emb + (size_t)bj * 64 + p * 8;
        float4 e0 = *(const float4*)(e);
        float4 e1 = *(const float4*)(e + 4);
        float4 zv0 = *(const float4*)&z_s[tok][p * 8];
        float4 zv1 = *(const float4*)&z_s[tok][p * 8 + 4];
        float df;
        df = e0.x - zv0.x; ls += (double)(df * df);
        df = e0.y - zv0.y; ls += (double)(df * df);
        df = e0.z - zv0.z; ls += (double)(df * df);
        df = e0.w - zv0.w; ls += (double)(df * df);
        df = e1.x - zv1.x; ls += (double)(df * df);
        df = e1.y - zv1.y; ls += (double)(df * df);
        df = e1.z - zv1.z; ls += (double)(df * df);
        df = e1.w - zv1.w; ls += (double)(df * df);
        *(float4*)&z_s[tok][p * 8] = e0;           // tile becomes z_q
        *(float4*)&z_s[tok][p * 8 + 4] = e1;
    }
    #pragma unroll
    for (int off = 32; off > 0; off >>= 1) ls += __shfl_down(ls, off, 64);
    if (lane == 0) wsum[w] = ls;
    __syncthreads();                               // z_s fully z_q; wsum ready
    if (tid == 0)
        lossPart[blockIdx.x] = wsum[0] + wsum[1] + wsum[2] + wsum[3];

    // coalesced z_q store (transpose back out of token-major LDS)
    {
        const int c = tid >> 2, u0 = (tid & 3) * 8;
        float4 f0, f1;
        f0.x = z_s[u0 + 0][c]; f0.y = z_s[u0 + 1][c];
        f0.z = z_s[u0 + 2][c]; f0.w = z_s[u0 + 3][c];
        f1.x = z_s[u0 + 4][c]; f1.y = z_s[u0 + 5][c];
        f1.z = z_s[u0 + 6][c]; f1.w = z_s[u0 + 7][c];
        float* dst = zq + (size_t)b * B_STRIDE + (size_t)c * CH_STRIDE + hw0 + u0;
        *(float4*)(dst) = f0;
        *(float4*)(dst + 4) = f1;
    }
}

__global__ __launch_bounds__(256) void vq_final(const int* __restrict__ hist,
                                                const double* __restrict__ lossPart,
                                                float* __restrict__ outs) {
    __shared__ double red[256];
    __shared__ double red2[256];
    double acc = 0.0;
    for (int j = threadIdx.x; j < NE; j += 256) {
        double em = (double)hist[j] * (1.0 / 65536.0);
        acc += em * log(em + 1e-10);
    }
    double lsum = 0.0;
    for (int j = threadIdx.x; j < 2048; j += 256) lsum += lossPart[j];
    red[threadIdx.x] = acc;
    red2[threadIdx.x] = lsum;
    __syncthreads();
    for (int s = 128; s > 0; s >>= 1) {
        if (threadIdx.x < s) {
            red[threadIdx.x] += red[threadIdx.x + s];
            red2[threadIdx.x] += red2[threadIdx.x + s];
        }
        __syncthreads();
    }
    if (threadIdx.x == 0) {
        outs[0] = (float)(1.25 * red2[0] * (1.0 / 4194304.0));
        outs[1] = (float)exp(-red[0]);
    }
}

extern "C" void kernel_launch(void* const* d_in, const int* in_sizes, int n_in,
                              void* d_out, int out_size, void* d_ws, size_t ws_size,
                              hipStream_t stream) {
    const float* z = (const float*)d_in[0];
    const float* emb = (const float*)d_in[1];
    float* out = (float*)d_out;

    char* ws = (char*)d_ws;
    ushort_t* efrag = (ushort_t*)ws;
    float* enorm = (float*)(ws + 131072);
    int* hist = (int*)(ws + 135168);
    double* lossPart = (double*)(ws + 143360);

    float* zq = out;                        // [0, 4194304)
    float* scalars = out + 4194304;         // loss, perplexity
    float* out_idx = out + 4194306;         // 65536 indices as float

    vq_prep_e<<<256, 256, 0, stream>>>(emb, efrag, enorm, hist);
    vq_main<<<2048, 256, 0, stream>>>(z, efrag, enorm, emb, zq, out_idx,
                                      hist, lossPart);
    vq_final<<<1, 256, 0, stream>>>(hist, lossPart, scalars);
}